// Round 3
// baseline (999.383 us; speedup 1.0000x reference)
//
#include <hip/hip_runtime.h>
#include <stdint.h>

#define EPS 1e-5f

typedef __attribute__((ext_vector_type(8))) __bf16 bf16x8;
typedef __attribute__((ext_vector_type(4))) float f32x4;
typedef __attribute__((ext_vector_type(16))) float f32x16;

__device__ __forceinline__ int swz4(int r) { return (r ^ (r >> 2)) & 3; }

__device__ __forceinline__ unsigned short f2bf(float f) {
  union { float f; unsigned u; } v; v.f = f;
  unsigned r = v.u + 0x7fffu + ((v.u >> 16) & 1u);
  return (unsigned short)(r >> 16);
}

__device__ __forceinline__ void glds16(const unsigned short* g, unsigned short* l) {
  __builtin_amdgcn_global_load_lds(
      (const __attribute__((address_space(1))) void*)g,
      (__attribute__((address_space(3))) void*)l, 16, 0, 0);
}

template <int N>
__device__ __forceinline__ void vmwait() {
  asm volatile("s_waitcnt vmcnt(%0)" ::"n"(N) : "memory");
}

// ---------------------------------------------------------------------------
// Pack W [c2][c1][13][13] f32 -> bf16 per-K-step tiles = exact linear LDS
// image of the A tile (chunk swizzle baked in).
// K order: k = ((kh*8 + c1c)*13 + kw)*32 + c1i
// Tile (c2t, ks): [m 128][slot 4][j 8], slot = (c1i>>3) ^ swz4(m)
// ---------------------------------------------------------------------------
__global__ __launch_bounds__(256) void pack_w_kernel(
    const float* __restrict__ W, unsigned short* __restrict__ Wp) {
  const int blk = blockIdx.x;  // c2*13 + kh
  const int c2 = blk / 13, kh = blk - c2 * 13;
  const int c1 = threadIdx.x;
  const int c2t = c2 >> 7, m = c2 & 127;
  const int c1c = c1 >> 5, c1i = c1 & 31;
  const float* src = W + (((size_t)(c2 * 256 + c1)) * 13 + kh) * 13;
  const int rowoff = (((c1i >> 3) ^ swz4(m)) << 3) + (c1i & 7);
#pragma unroll
  for (int kw = 0; kw < 13; ++kw) {
    const int ks = (kh * 8 + c1c) * 13 + kw;
    const size_t dst = (((size_t)c2t * 1352 + ks) * 128 + m) * 32 + rowoff;
    Wp[dst] = f2bf(src[kw]);
  }
}

// ---------------------------------------------------------------------------
// Pack x [b][c1][64][64] f32 -> xT[b][c1c][rowp 76][colp 80][c1i 32] bf16,
// zero-padded halo (rowp = row+6, colp = ic+8), chunk swizzle baked in.
// ---------------------------------------------------------------------------
__global__ __launch_bounds__(256) void pack_xt_kernel(
    const float* __restrict__ x, unsigned short* __restrict__ xT) {
  const int blk = blockIdx.x;  // (b*8 + c1c)*76 + rowp ; 4864 blocks
  const int rowp = blk % 76;
  const int bc = blk / 76;
  const int c1c = bc & 7, b = bc >> 3;
  const int row = rowp - 6;
  const bool rok = (unsigned)row < 64u;
  unsigned short* dst = xT + (size_t)blk * 2560;
  const float* srcb = x + (size_t)(b * 256 + c1c * 32) * 4096 +
                      (rok ? row * 64 : 0);
#pragma unroll
  for (int e = 0; e < 10; ++e) {
    const int idx = e * 256 + threadIdx.x;  // 0..2559
    const int colp = idx >> 5, c1i = idx & 31;
    const int ic = colp - 8;
    const float v = (rok && (unsigned)ic < 64u) ? srcb[(size_t)c1i * 4096 + ic] : 0.f;
    dst[colp * 32 + ((((c1i >> 3) ^ swz4(colp)) << 3)) + (c1i & 7)] = f2bf(v);
  }
}

// ---------------------------------------------------------------------------
// Implicit-GEMM conv + BN + SiLU.
// Block: 256 thr (4 waves, 2M x 2N), tile = 128 c2 x 256 spatial (4h x 64w).
// Per-wave output 64 c2 x 128 spatial via 32x32x16 MFMA (2 mt x 4 nt).
// Grid: 256 = 2 c2t x 8 b x 16 h-blocks. 1 block/CU.
// ---------------------------------------------------------------------------
__global__ __launch_bounds__(256, 2) void conv3_kernel(
    const unsigned short* __restrict__ Wp, const unsigned short* __restrict__ xT,
    const float* __restrict__ gamma, const float* __restrict__ beta,
    const float* __restrict__ mean, const float* __restrict__ var,
    float* __restrict__ out) {
  __shared__ __align__(16) unsigned short Albuf[2][4096];   // 2 x 8 KiB
  __shared__ __align__(16) unsigned short Wbuf[2][10240];   // 2 x 20 KiB
  __shared__ float s_scale[128], s_shift[128];

  const int tid = threadIdx.x;
  const int bid = blockIdx.x;
  const int b = bid & 7;  // XCD-aware: all blocks on XCD k share batch image k
  const int rest = bid >> 3;
  const int h0 = (rest & 15) * 4;
  const int c2t = rest >> 4;

  const int wid = tid >> 6, lane = tid & 63;
  const int wr = wid >> 1, wc = wid & 1;
  const int l31 = lane & 31, hi2 = lane >> 5;

  if (tid < 128) {
    const int c2 = c2t * 128 + tid;
    const float inv = gamma[c2] * rsqrtf(var[c2] + EPS);
    s_scale[tid] = inv;
    s_shift[tid] = beta[c2] - mean[c2] * inv;
  }

  // A-fragment byte offsets: m = wr*64 + mt*32 + l31, chunk = ks*2 + hi2
  int aoff[2][2];
#pragma unroll
  for (int mt = 0; mt < 2; ++mt)
#pragma unroll
    for (int ks = 0; ks < 2; ++ks) {
      const int m = wr * 64 + mt * 32 + l31;
      aoff[mt][ks] = m * 64 + (((ks * 2 + hi2) ^ swz4(m)) << 4);
    }
  // B-fragment spatial decomposition: n = wc*128 + nt*32 + l31
  int ndh[4], nwl[4];
#pragma unroll
  for (int nt = 0; nt < 4; ++nt) {
    const int n = wc * 128 + nt * 32 + l31;
    ndh[nt] = n >> 6;
    nwl[nt] = n & 63;
  }

  const int aSrcOff = wid * 1024 + lane * 8;  // ushort units
  const int aDstOff = wid * 1024;
  const int wSrcOff = wid * 512 + lane * 8;
  const int wDstOff = wid * 512;

  const size_t c2base = (size_t)c2t * 1352;
  const int bc8 = b * 8;

  auto wtile = [&](int T) -> const unsigned short* {
    const int kh = T >> 3, c1c = T & 7;
    return xT + (size_t)((bc8 + c1c) * 76 + h0 + kh) * 2560;
  };

  f32x16 acc[2][4];
#pragma unroll
  for (int i = 0; i < 2; ++i)
#pragma unroll
    for (int j = 0; j < 4; ++j)
#pragma unroll
      for (int r = 0; r < 16; ++r) acc[i][j][r] = 0.f;

  // ---- prologue: A(0) -> Albuf[0], window(T=0) -> Wbuf[0] (5 rounds)
  {
    const unsigned short* at = Wp + (c2base << 12);
    glds16(at + aSrcOff, &Albuf[0][aDstOff]);
    glds16(at + aSrcOff + 512, &Albuf[0][aDstOff + 512]);
    const unsigned short* ws = wtile(0);
#pragma unroll
    for (int r = 0; r < 5; ++r)
      glds16(ws + r * 2048 + wSrcOff, &Wbuf[0][r * 2048 + wDstOff]);
  }

// one K=32 step: prefetch A(s+1) (+ one window round on kw 8..12), counted
// vmcnt, raw barriers, 12 ds_read_b128 + 16 MFMA(32x32x16), lgkm drain.
#define STEP3(KW, AP, WPX, TT, WSN)                                           \
  {                                                                           \
    {                                                                         \
      int sn = (TT) * 13 + (KW) + 1;                                          \
      if (sn == 1352) sn = 0;                                                 \
      const unsigned short* at = Wp + ((c2base + (size_t)sn) << 12);          \
      glds16(at + aSrcOff, &Albuf[(AP) ^ 1][aDstOff]);                        \
      glds16(at + aSrcOff + 512, &Albuf[(AP) ^ 1][aDstOff + 512]);            \
    }                                                                         \
    if ((KW) >= 8) {                                                          \
      glds16((WSN) + ((KW) - 8) * 2048 + wSrcOff,                             \
             &Wbuf[(WPX) ^ 1][((KW) - 8) * 2048 + wDstOff]);                  \
    }                                                                         \
    vmwait<(((KW) >= 8) ? 3 : 2)>();                                          \
    __builtin_amdgcn_s_barrier();                                             \
    asm volatile("" ::: "memory");                                            \
    {                                                                         \
      const char* ab = (const char*)&Albuf[(AP)][0];                          \
      const char* wb = (const char*)&Wbuf[(WPX)][0];                          \
      _Pragma("unroll") for (int ks = 0; ks < 2; ++ks) {                      \
        const bf16x8 a0 = *(const bf16x8*)(ab + aoff[0][ks]);                 \
        const bf16x8 a1 = *(const bf16x8*)(ab + aoff[1][ks]);                 \
        bf16x8 bfr[4];                                                        \
        _Pragma("unroll") for (int nt = 0; nt < 4; ++nt) {                    \
          const int wcoln = nwl[nt] + (KW) + 2;                               \
          bfr[nt] = *(const bf16x8*)(wb + (ndh[nt] * 80 + wcoln) * 64 +       \
                                     (((ks * 2 + hi2) ^ swz4(wcoln)) << 4));  \
        }                                                                     \
        _Pragma("unroll") for (int nt = 0; nt < 4; ++nt) {                    \
          acc[0][nt] = __builtin_amdgcn_mfma_f32_32x32x16_bf16(               \
              a0, bfr[nt], acc[0][nt], 0, 0, 0);                              \
          acc[1][nt] = __builtin_amdgcn_mfma_f32_32x32x16_bf16(               \
              a1, bfr[nt], acc[1][nt], 0, 0, 0);                              \
        }                                                                     \
      }                                                                       \
    }                                                                         \
    asm volatile("s_waitcnt lgkmcnt(0)" ::: "memory");                        \
    __builtin_amdgcn_s_barrier();                                             \
  }

  for (int u = 0; u < 52; ++u) {
    const int T0 = u * 2, T1 = T0 + 1;
    const unsigned short* wsN1 = wtile(T1);
    const unsigned short* wsN2 = wtile((T1 + 1 == 104) ? 0 : T1 + 1);
    STEP3(0, 0, 0, T0, wsN1)
    STEP3(1, 1, 0, T0, wsN1)
    STEP3(2, 0, 0, T0, wsN1)
    STEP3(3, 1, 0, T0, wsN1)
    STEP3(4, 0, 0, T0, wsN1)
    STEP3(5, 1, 0, T0, wsN1)
    STEP3(6, 0, 0, T0, wsN1)
    STEP3(7, 1, 0, T0, wsN1)
    STEP3(8, 0, 0, T0, wsN1)
    STEP3(9, 1, 0, T0, wsN1)
    STEP3(10, 0, 0, T0, wsN1)
    STEP3(11, 1, 0, T0, wsN1)
    STEP3(12, 0, 0, T0, wsN1)
    STEP3(0, 1, 1, T1, wsN2)
    STEP3(1, 0, 1, T1, wsN2)
    STEP3(2, 1, 1, T1, wsN2)
    STEP3(3, 0, 1, T1, wsN2)
    STEP3(4, 1, 1, T1, wsN2)
    STEP3(5, 0, 1, T1, wsN2)
    STEP3(6, 1, 1, T1, wsN2)
    STEP3(7, 0, 1, T1, wsN2)
    STEP3(8, 1, 1, T1, wsN2)
    STEP3(9, 0, 1, T1, wsN2)
    STEP3(10, 1, 1, T1, wsN2)
    STEP3(11, 0, 1, T1, wsN2)
    STEP3(12, 1, 1, T1, wsN2)
  }
#undef STEP3

  // ---- epilogue: BN + SiLU.
  // 32x32 C/D layout (m74/m101): col = lane&31, row = (r&3)+8*(r>>2)+4*(lane>>5)
#pragma unroll
  for (int mt = 0; mt < 2; ++mt) {
#pragma unroll
    for (int nt = 0; nt < 4; ++nt) {
      const int n = wc * 128 + nt * 32 + l31;
      const int hh = h0 + (n >> 6), ww = n & 63;
#pragma unroll
      for (int r = 0; r < 16; ++r) {
        const int mloc = (r & 3) + 8 * (r >> 2) + 4 * hi2;
        const int c2l = wr * 64 + mt * 32 + mloc;
        const float y = acc[mt][nt][r] * s_scale[c2l] + s_shift[c2l];
        out[((size_t)(b * 256 + c2t * 128 + c2l)) * 4096 + hh * 64 + ww] =
            y / (1.f + __expf(-y));
      }
    }
  }
}

// ---------------------------------------------------------------------------
// Safety-net fallback if workspace is too small for packed buffers.
// ---------------------------------------------------------------------------
__global__ void naive_conv_kernel(
    const float* __restrict__ x, const float* __restrict__ W,
    const float* __restrict__ gamma, const float* __restrict__ beta,
    const float* __restrict__ mean, const float* __restrict__ var,
    float* __restrict__ out) {
  const int idx = blockIdx.x * 256 + threadIdx.x;
  if (idx >= 8 * 256 * 64 * 64) return;
  const int w = idx & 63, h = (idx >> 6) & 63;
  const int c2 = (idx >> 12) & 255, b = idx >> 20;
  float s = 0.f;
  for (int c1 = 0; c1 < 256; ++c1) {
    const float* xp = x + ((size_t)(b * 256 + c1) * 4096);
    const float* wp = W + ((size_t)(c2 * 256 + c1) * 169);
    for (int kh = 0; kh < 13; ++kh) {
      const int r = h + kh - 6;
      if ((unsigned)r >= 64u) continue;
      for (int kw = 0; kw < 13; ++kw) {
        const int c = w + kw - 6;
        if ((unsigned)c >= 64u) continue;
        s += xp[r * 64 + c] * wp[kh * 13 + kw];
      }
    }
  }
  const float inv = gamma[c2] * rsqrtf(var[c2] + EPS);
  const float y = s * inv + (beta[c2] - mean[c2] * inv);
  out[idx] = y / (1.f + __expf(-y));
}

extern "C" void kernel_launch(void* const* d_in, const int* in_sizes, int n_in,
                              void* d_out, int out_size, void* d_ws, size_t ws_size,
                              hipStream_t stream) {
  const float* x = (const float*)d_in[0];
  const float* W = (const float*)d_in[1];
  const float* gamma = (const float*)d_in[2];
  const float* beta = (const float*)d_in[3];
  const float* mean = (const float*)d_in[4];
  const float* var = (const float*)d_in[5];
  float* out = (float*)d_out;

  const size_t WP_BYTES = (size_t)256 * 43264 * 2;  // 22,151,168
  const size_t XT_BYTES = (size_t)12455424 * 2;     // 24,910,848

  if (ws_size >= WP_BYTES + XT_BYTES) {
    unsigned short* Wp = (unsigned short*)d_ws;
    unsigned short* xT = (unsigned short*)((char*)d_ws + WP_BYTES);
    pack_w_kernel<<<256 * 13, 256, 0, stream>>>(W, Wp);
    pack_xt_kernel<<<8 * 8 * 76, 256, 0, stream>>>(x, xT);
    conv3_kernel<<<256, 256, 0, stream>>>(Wp, xT, gamma, beta, mean, var, out);
  } else {
    naive_conv_kernel<<<(8 * 256 * 64 * 64 + 255) / 256, 256, 0, stream>>>(
        x, W, gamma, beta, mean, var, out);
  }
}

// Round 4
// 797.155 us; speedup vs baseline: 1.2537x; 1.2537x over previous
//
#include <hip/hip_runtime.h>
#include <stdint.h>

#define EPS 1e-5f

typedef __attribute__((ext_vector_type(8))) __bf16 bf16x8;
typedef __attribute__((ext_vector_type(16))) float f32x16;

__device__ __forceinline__ int swz4(int r) { return (r ^ (r >> 2)) & 3; }

__device__ __forceinline__ unsigned short f2bf(float f) {
  union { float f; unsigned u; } v; v.f = f;
  unsigned r = v.u + 0x7fffu + ((v.u >> 16) & 1u);
  return (unsigned short)(r >> 16);
}

__device__ __forceinline__ void glds16(const unsigned short* g, unsigned short* l) {
  __builtin_amdgcn_global_load_lds(
      (const __attribute__((address_space(1))) void*)g,
      (__attribute__((address_space(3))) void*)l, 16, 0, 0);
}
__device__ __forceinline__ void glds4(const unsigned short* g, unsigned short* l) {
  __builtin_amdgcn_global_load_lds(
      (const __attribute__((address_space(1))) void*)g,
      (__attribute__((address_space(3))) void*)l, 4, 0, 0);
}

template <int N>
__device__ __forceinline__ void vmwait() {
  asm volatile("s_waitcnt vmcnt(%0)" ::"n"(N) : "memory");
}

// ---------------------------------------------------------------------------
// Pack W [c2][c1][13][13] f32 -> bf16 per-K-step tiles = exact linear LDS
// image of the A tile (chunk swizzle baked in).
// K order: k = ((kh*8 + c1c)*13 + kw)*32 + c1i
// ---------------------------------------------------------------------------
__global__ __launch_bounds__(256) void pack_w_kernel(
    const float* __restrict__ W, unsigned short* __restrict__ Wp) {
  const int blk = blockIdx.x;  // c2*13 + kh
  const int c2 = blk / 13, kh = blk - c2 * 13;
  const int c1 = threadIdx.x;
  const int c2t = c2 >> 7, m = c2 & 127;
  const int c1c = c1 >> 5, c1i = c1 & 31;
  const float* src = W + (((size_t)(c2 * 256 + c1)) * 13 + kh) * 13;
  const int rowoff = (((c1i >> 3) ^ swz4(m)) << 3) + (c1i & 7);
#pragma unroll
  for (int kw = 0; kw < 13; ++kw) {
    const int ks = (kh * 8 + c1c) * 13 + kw;
    const size_t dst = (((size_t)c2t * 1352 + ks) * 128 + m) * 32 + rowoff;
    Wp[dst] = f2bf(src[kw]);
  }
}

// ---------------------------------------------------------------------------
// Pack x [b][c1][64][64] f32 -> xT[b][c1c][rowp 76][colp 80][c1i 32] bf16,
// zero-padded halo (rowp = row+6, colp = ic+8), chunk swizzle baked in.
// ---------------------------------------------------------------------------
__global__ __launch_bounds__(256) void pack_xt_kernel(
    const float* __restrict__ x, unsigned short* __restrict__ xT) {
  const int blk = blockIdx.x;  // (b*8 + c1c)*76 + rowp ; 4864 blocks
  const int rowp = blk % 76;
  const int bc = blk / 76;
  const int c1c = bc & 7, b = bc >> 3;
  const int row = rowp - 6;
  const bool rok = (unsigned)row < 64u;
  unsigned short* dst = xT + (size_t)blk * 2560;
  const float* srcb = x + (size_t)(b * 256 + c1c * 32) * 4096 +
                      (rok ? row * 64 : 0);
#pragma unroll
  for (int e = 0; e < 10; ++e) {
    const int idx = e * 256 + threadIdx.x;  // 0..2559
    const int colp = idx >> 5, c1i = idx & 31;
    const int ic = colp - 8;
    const float v = (rok && (unsigned)ic < 64u) ? srcb[(size_t)c1i * 4096 + ic] : 0.f;
    dst[colp * 32 + ((((c1i >> 3) ^ swz4(colp)) << 3)) + (c1i & 7)] = f2bf(v);
  }
}

// ---------------------------------------------------------------------------
// Implicit-GEMM conv + BN + SiLU.
// Block: 512 thr (8 waves, 2M x 4N), tile = 128 c2 x 256 spatial (4h x 64w).
// Wave tile 64 c2 x 64 sp via 32x32x16 MFMA (2 mt x 2 nt), 2 waves/SIMD.
// Grid: 256 = 2 c2t x 8 b x 16 h-blocks. 1 block/CU.
// ---------------------------------------------------------------------------
__global__ __launch_bounds__(512, 2) void conv4_kernel(
    const unsigned short* __restrict__ Wp, const unsigned short* __restrict__ xT,
    const float* __restrict__ gamma, const float* __restrict__ beta,
    const float* __restrict__ mean, const float* __restrict__ var,
    float* __restrict__ out) {
  __shared__ __align__(16) unsigned short Albuf[2][4096];   // 2 x 8 KiB
  __shared__ __align__(16) unsigned short Wbuf[2][10240];   // 2 x 20 KiB
  __shared__ float s_scale[128], s_shift[128];

  const int tid = threadIdx.x;
  const int bid = blockIdx.x;
  const int b = bid & 7;  // XCD-aware: all blocks on XCD k share batch image k
  const int rest = bid >> 3;
  const int h0 = (rest & 15) * 4;
  const int c2t = rest >> 4;

  const int wid = tid >> 6, lane = tid & 63;
  const int wr = wid >> 2, wn = wid & 3;  // 2M x 4N wave grid
  const int l31 = lane & 31, hi2 = lane >> 5;

  if (tid < 128) {
    const int c2 = c2t * 128 + tid;
    const float inv = gamma[c2] * rsqrtf(var[c2] + EPS);
    s_scale[tid] = inv;
    s_shift[tid] = beta[c2] - mean[c2] * inv;
  }

  // A-fragment byte offsets: m = wr*64 + mt*32 + l31, chunk = ks*2 + hi2
  int aoff[2][2];
#pragma unroll
  for (int mt = 0; mt < 2; ++mt)
#pragma unroll
    for (int ks = 0; ks < 2; ++ks) {
      const int m = wr * 64 + mt * 32 + l31;
      aoff[mt][ks] = m * 64 + (((ks * 2 + hi2) ^ swz4(m)) << 4);
    }
  // B-fragment spatial decomposition: n = wn*64 + nt*32 + l31
  int ndh[2], nwl[2];
#pragma unroll
  for (int nt = 0; nt < 2; ++nt) {
    const int n = wn * 64 + nt * 32 + l31;
    ndh[nt] = n >> 6;
    nwl[nt] = n & 63;
  }

  // staging offsets (ushort units)
  const int aSrc = tid * 8;
  const int aDst = wid * 512;
  const int w16Src = tid * 8;          // rounds 0,1 (+r*4096)
  const int w16Dst = wid * 512;
  const int w4Src = 8192 + tid * 2;    // rounds 2a,2b (+0 / +1024)
  const int w4Dst = 8192 + wid * 128;

  const size_t c2base = (size_t)c2t * 1352;
  const int bc8 = b * 8;

  auto wtile = [&](int T) -> const unsigned short* {
    const int kh = T >> 3, c1c = T & 7;
    return xT + (size_t)((bc8 + c1c) * 76 + h0 + kh) * 2560;
  };

  f32x16 acc[2][2];
#pragma unroll
  for (int i = 0; i < 2; ++i)
#pragma unroll
    for (int j = 0; j < 2; ++j)
#pragma unroll
      for (int r = 0; r < 16; ++r) acc[i][j][r] = 0.f;

  // ---- prologue: A(0) -> Albuf[0], window(T=0) -> Wbuf[0]
  {
    const unsigned short* at = Wp + (c2base << 12);
    glds16(at + aSrc, &Albuf[0][aDst]);
    const unsigned short* ws = wtile(0);
    glds16(ws + w16Src, &Wbuf[0][w16Dst]);
    glds16(ws + 4096 + w16Src, &Wbuf[0][4096 + w16Dst]);
    glds4(ws + w4Src, &Wbuf[0][w4Dst]);
    glds4(ws + 1024 + w4Src, &Wbuf[0][1024 + w4Dst]);
  }

// one K=32 step: prefetch A(s+1) (+ window rounds on kw 8..10), counted
// vmcnt, raw barriers, 8 ds_read_b128 + 8 MFMA(32x32x16), lgkm drain.
#define STEP4(KW, AP, WPX, TT, WSN)                                           \
  {                                                                           \
    {                                                                         \
      int sn = (TT) * 13 + (KW) + 1;                                          \
      if (sn == 1352) sn = 0;                                                 \
      const unsigned short* at = Wp + ((c2base + (size_t)sn) << 12);          \
      glds16(at + aSrc, &Albuf[(AP) ^ 1][aDst]);                              \
    }                                                                         \
    if ((KW) == 8) glds16((WSN) + w16Src, &Wbuf[(WPX) ^ 1][w16Dst]);          \
    if ((KW) == 9)                                                            \
      glds16((WSN) + 4096 + w16Src, &Wbuf[(WPX) ^ 1][4096 + w16Dst]);         \
    if ((KW) == 10) {                                                         \
      glds4((WSN) + w4Src, &Wbuf[(WPX) ^ 1][w4Dst]);                          \
      glds4((WSN) + 1024 + w4Src, &Wbuf[(WPX) ^ 1][1024 + w4Dst]);            \
    }                                                                         \
    vmwait<(((KW) == 10) ? 3 : (((KW) == 8 || (KW) == 9) ? 2 : 1))>();        \
    __builtin_amdgcn_s_barrier();                                             \
    asm volatile("" ::: "memory");                                            \
    {                                                                         \
      const char* ab = (const char*)&Albuf[(AP)][0];                          \
      const char* wb = (const char*)&Wbuf[(WPX)][0];                          \
      __builtin_amdgcn_s_setprio(1);                                          \
      _Pragma("unroll") for (int ks = 0; ks < 2; ++ks) {                      \
        const bf16x8 a0 = *(const bf16x8*)(ab + aoff[0][ks]);                 \
        const bf16x8 a1 = *(const bf16x8*)(ab + aoff[1][ks]);                 \
        bf16x8 bfr[2];                                                        \
        _Pragma("unroll") for (int nt = 0; nt < 2; ++nt) {                    \
          const int wcoln = nwl[nt] + (KW) + 2;                               \
          bfr[nt] = *(const bf16x8*)(wb + (ndh[nt] * 80 + wcoln) * 64 +       \
                                     (((ks * 2 + hi2) ^ swz4(wcoln)) << 4));  \
        }                                                                     \
        _Pragma("unroll") for (int nt = 0; nt < 2; ++nt) {                    \
          acc[0][nt] = __builtin_amdgcn_mfma_f32_32x32x16_bf16(               \
              a0, bfr[nt], acc[0][nt], 0, 0, 0);                              \
          acc[1][nt] = __builtin_amdgcn_mfma_f32_32x32x16_bf16(               \
              a1, bfr[nt], acc[1][nt], 0, 0, 0);                              \
        }                                                                     \
      }                                                                       \
      __builtin_amdgcn_s_setprio(0);                                          \
    }                                                                         \
    asm volatile("s_waitcnt lgkmcnt(0)" ::: "memory");                        \
    __builtin_amdgcn_s_barrier();                                             \
  }

  for (int u = 0; u < 52; ++u) {
    const int T0 = u * 2, T1 = T0 + 1;
    const unsigned short* wsN1 = wtile(T1);
    const unsigned short* wsN2 = wtile((T1 + 1 == 104) ? 0 : T1 + 1);
    STEP4(0, 0, 0, T0, wsN1)
    STEP4(1, 1, 0, T0, wsN1)
    STEP4(2, 0, 0, T0, wsN1)
    STEP4(3, 1, 0, T0, wsN1)
    STEP4(4, 0, 0, T0, wsN1)
    STEP4(5, 1, 0, T0, wsN1)
    STEP4(6, 0, 0, T0, wsN1)
    STEP4(7, 1, 0, T0, wsN1)
    STEP4(8, 0, 0, T0, wsN1)
    STEP4(9, 1, 0, T0, wsN1)
    STEP4(10, 0, 0, T0, wsN1)
    STEP4(11, 1, 0, T0, wsN1)
    STEP4(12, 0, 0, T0, wsN1)
    STEP4(0, 1, 1, T1, wsN2)
    STEP4(1, 0, 1, T1, wsN2)
    STEP4(2, 1, 1, T1, wsN2)
    STEP4(3, 0, 1, T1, wsN2)
    STEP4(4, 1, 1, T1, wsN2)
    STEP4(5, 0, 1, T1, wsN2)
    STEP4(6, 1, 1, T1, wsN2)
    STEP4(7, 0, 1, T1, wsN2)
    STEP4(8, 1, 1, T1, wsN2)
    STEP4(9, 0, 1, T1, wsN2)
    STEP4(10, 1, 1, T1, wsN2)
    STEP4(11, 0, 1, T1, wsN2)
    STEP4(12, 1, 1, T1, wsN2)
  }
#undef STEP4

  vmwait<0>();  // drain final dangling prefetch

  // ---- epilogue: BN + SiLU.
  // 32x32 C/D layout (m74/m101): col = lane&31, row = (r&3)+8*(r>>2)+4*(lane>>5)
#pragma unroll
  for (int mt = 0; mt < 2; ++mt) {
#pragma unroll
    for (int nt = 0; nt < 2; ++nt) {
      const int n = wn * 64 + nt * 32 + l31;
      const int hh = h0 + (n >> 6), ww = n & 63;
#pragma unroll
      for (int r = 0; r < 16; ++r) {
        const int mloc = (r & 3) + 8 * (r >> 2) + 4 * hi2;
        const int c2l = wr * 64 + mt * 32 + mloc;
        const float y = acc[mt][nt][r] * s_scale[c2l] + s_shift[c2l];
        out[((size_t)(b * 256 + c2t * 128 + c2l)) * 4096 + hh * 64 + ww] =
            y / (1.f + __expf(-y));
      }
    }
  }
}

// ---------------------------------------------------------------------------
// Safety-net fallback if workspace is too small for packed buffers.
// ---------------------------------------------------------------------------
__global__ void naive_conv_kernel(
    const float* __restrict__ x, const float* __restrict__ W,
    const float* __restrict__ gamma, const float* __restrict__ beta,
    const float* __restrict__ mean, const float* __restrict__ var,
    float* __restrict__ out) {
  const int idx = blockIdx.x * 256 + threadIdx.x;
  if (idx >= 8 * 256 * 64 * 64) return;
  const int w = idx & 63, h = (idx >> 6) & 63;
  const int c2 = (idx >> 12) & 255, b = idx >> 20;
  float s = 0.f;
  for (int c1 = 0; c1 < 256; ++c1) {
    const float* xp = x + ((size_t)(b * 256 + c1) * 4096);
    const float* wp = W + ((size_t)(c2 * 256 + c1) * 169);
    for (int kh = 0; kh < 13; ++kh) {
      const int r = h + kh - 6;
      if ((unsigned)r >= 64u) continue;
      for (int kw = 0; kw < 13; ++kw) {
        const int c = w + kw - 6;
        if ((unsigned)c >= 64u) continue;
        s += xp[r * 64 + c] * wp[kh * 13 + kw];
      }
    }
  }
  const float inv = gamma[c2] * rsqrtf(var[c2] + EPS);
  const float y = s * inv + (beta[c2] - mean[c2] * inv);
  out[idx] = y / (1.f + __expf(-y));
}

extern "C" void kernel_launch(void* const* d_in, const int* in_sizes, int n_in,
                              void* d_out, int out_size, void* d_ws, size_t ws_size,
                              hipStream_t stream) {
  const float* x = (const float*)d_in[0];
  const float* W = (const float*)d_in[1];
  const float* gamma = (const float*)d_in[2];
  const float* beta = (const float*)d_in[3];
  const float* mean = (const float*)d_in[4];
  const float* var = (const float*)d_in[5];
  float* out = (float*)d_out;

  const size_t WP_BYTES = (size_t)256 * 43264 * 2;  // 22,151,168
  const size_t XT_BYTES = (size_t)12455424 * 2;     // 24,910,848

  if (ws_size >= WP_BYTES + XT_BYTES) {
    unsigned short* Wp = (unsigned short*)d_ws;
    unsigned short* xT = (unsigned short*)((char*)d_ws + WP_BYTES);
    pack_w_kernel<<<256 * 13, 256, 0, stream>>>(W, Wp);
    pack_xt_kernel<<<8 * 8 * 76, 256, 0, stream>>>(x, xT);
    conv4_kernel<<<256, 512, 0, stream>>>(Wp, xT, gamma, beta, mean, var, out);
  } else {
    naive_conv_kernel<<<(8 * 256 * 64 * 64 + 255) / 256, 256, 0, stream>>>(
        x, W, gamma, beta, mean, var, out);
  }
}

// Round 5
// 641.637 us; speedup vs baseline: 1.5576x; 1.2424x over previous
//
#include <hip/hip_runtime.h>
#include <stdint.h>

#define EPS 1e-5f

typedef __attribute__((ext_vector_type(8))) __bf16 bf16x8;
typedef __attribute__((ext_vector_type(16))) float f32x16;

__device__ __forceinline__ int swz4(int r) { return (r ^ (r >> 2)) & 3; }

__device__ __forceinline__ unsigned short f2bf(float f) {
  union { float f; unsigned u; } v; v.f = f;
  unsigned r = v.u + 0x7fffu + ((v.u >> 16) & 1u);
  return (unsigned short)(r >> 16);
}

__device__ __forceinline__ void glds16(const unsigned short* g, unsigned short* l) {
  __builtin_amdgcn_global_load_lds(
      (const __attribute__((address_space(1))) void*)g,
      (__attribute__((address_space(3))) void*)l, 16, 0, 0);
}
__device__ __forceinline__ void glds4(const unsigned short* g, unsigned short* l) {
  __builtin_amdgcn_global_load_lds(
      (const __attribute__((address_space(1))) void*)g,
      (__attribute__((address_space(3))) void*)l, 4, 0, 0);
}

template <int N>
__device__ __forceinline__ void vmwait() {
  asm volatile("s_waitcnt vmcnt(%0)" ::"n"(N) : "memory");
}

// ---------------------------------------------------------------------------
// Pack W [c2][c1][13][13] f32 -> bf16 per-K-step tiles = exact linear LDS
// image of the A tile (chunk swizzle baked in).
// K order: k = ((kh*8 + c1c)*13 + kw)*32 + c1i
// ---------------------------------------------------------------------------
__global__ __launch_bounds__(256) void pack_w_kernel(
    const float* __restrict__ W, unsigned short* __restrict__ Wp) {
  const int blk = blockIdx.x;  // c2*13 + kh
  const int c2 = blk / 13, kh = blk - c2 * 13;
  const int c1 = threadIdx.x;
  const int c2t = c2 >> 7, m = c2 & 127;
  const int c1c = c1 >> 5, c1i = c1 & 31;
  const float* src = W + (((size_t)(c2 * 256 + c1)) * 13 + kh) * 13;
  const int rowoff = (((c1i >> 3) ^ swz4(m)) << 3) + (c1i & 7);
#pragma unroll
  for (int kw = 0; kw < 13; ++kw) {
    const int ks = (kh * 8 + c1c) * 13 + kw;
    const size_t dst = (((size_t)c2t * 1352 + ks) * 128 + m) * 32 + rowoff;
    Wp[dst] = f2bf(src[kw]);
  }
}

// ---------------------------------------------------------------------------
// Pack x [b][c1][64][64] f32 -> xT[b][c1c][rowp 76][colp 80][c1i 32] bf16,
// zero-padded halo (rowp = row+6, colp = ic+8), chunk swizzle baked in.
// ---------------------------------------------------------------------------
__global__ __launch_bounds__(256) void pack_xt_kernel(
    const float* __restrict__ x, unsigned short* __restrict__ xT) {
  const int blk = blockIdx.x;  // (b*8 + c1c)*76 + rowp ; 4864 blocks
  const int rowp = blk % 76;
  const int bc = blk / 76;
  const int c1c = bc & 7, b = bc >> 3;
  const int row = rowp - 6;
  const bool rok = (unsigned)row < 64u;
  unsigned short* dst = xT + (size_t)blk * 2560;
  const float* srcb = x + (size_t)(b * 256 + c1c * 32) * 4096 +
                      (rok ? row * 64 : 0);
#pragma unroll
  for (int e = 0; e < 10; ++e) {
    const int idx = e * 256 + threadIdx.x;  // 0..2559
    const int colp = idx >> 5, c1i = idx & 31;
    const int ic = colp - 8;
    const float v = (rok && (unsigned)ic < 64u) ? srcb[(size_t)c1i * 4096 + ic] : 0.f;
    dst[colp * 32 + ((((c1i >> 3) ^ swz4(colp)) << 3)) + (c1i & 7)] = f2bf(v);
  }
}

// ---------------------------------------------------------------------------
// Implicit-GEMM conv + BN + SiLU.
// Block: 256 thr (4 waves 2M x 2N), tile 128 c2 x 128 sp (2h x 64w).
// Wave tile 64x64 via 32x32x16 MFMA. Grid 512 -> 2 independent blocks/CU.
// K=64 phases: 2 kw-steps per barrier pair; 26-phase static schedule.
// ---------------------------------------------------------------------------
__global__ __launch_bounds__(256, 2) void conv5_kernel(
    const unsigned short* __restrict__ Wp, const unsigned short* __restrict__ xT,
    const float* __restrict__ gamma, const float* __restrict__ beta,
    const float* __restrict__ mean, const float* __restrict__ var,
    float* __restrict__ out) {
  __shared__ __align__(16) unsigned short Abuf[2][8192];  // 2 x 16 KiB (2 tiles each)
  __shared__ __align__(16) unsigned short Wbuf[2][5120];  // 2 x 10 KiB (2 rows)
  __shared__ float s_scale[128], s_shift[128];

  const int tid = threadIdx.x;
  const int bid = blockIdx.x;
  const int b = bid & 7;  // XCD-aware: blocks on XCD k share batch image k
  const int h0 = ((bid >> 3) & 31) * 2;
  const int c2t = bid >> 8;

  const int wid = tid >> 6, lane = tid & 63;
  const int wr = wid >> 1, wc = wid & 1;
  const int l31 = lane & 31, hi2 = lane >> 5;

  if (tid < 128) {
    const int c2 = c2t * 128 + tid;
    const float inv = gamma[c2] * rsqrtf(var[c2] + EPS);
    s_scale[tid] = inv;
    s_shift[tid] = beta[c2] - mean[c2] * inv;
  }

  // A-fragment byte offsets within a 4096-ushort tile
  int aoff[2][2];
#pragma unroll
  for (int mt = 0; mt < 2; ++mt)
#pragma unroll
    for (int ks = 0; ks < 2; ++ks) {
      const int m = wr * 64 + mt * 32 + l31;
      aoff[mt][ks] = m * 64 + (((ks * 2 + hi2) ^ swz4(m)) << 4);
    }
  int ndh[2], nwl[2];
#pragma unroll
  for (int nt = 0; nt < 2; ++nt) {
    const int n = wc * 64 + nt * 32 + l31;
    ndh[nt] = n >> 6;
    nwl[nt] = n & 63;
  }

  const int tid8 = tid * 8, tid2 = tid * 2;
  const int widA = wid * 512, wid128 = wid * 128;

  const size_t c2base = (size_t)c2t * 1352;
  const int bc8 = b * 8;

  auto wtile = [&](int T) -> const unsigned short* {
    const int kh = T >> 3, c1c = T & 7;
    return xT + (size_t)((bc8 + c1c) * 76 + h0 + kh) * 2560;
  };

  f32x16 acc[2][2];
#pragma unroll
  for (int i = 0; i < 2; ++i)
#pragma unroll
    for (int j = 0; j < 2; ++j)
#pragma unroll
      for (int r = 0; r < 16; ++r) acc[i][j][r] = 0.f;

  // ---- prologue: A steps 0,1 -> Abuf[0]; window tile0 -> Wbuf[0]
  {
    const unsigned short* at0 = Wp + (c2base << 12);
    const unsigned short* at1 = Wp + ((c2base + 1) << 12);
    glds16(at0 + tid8, &Abuf[0][0] + widA);
    glds16(at0 + 2048 + tid8, &Abuf[0][2048] + widA);
    glds16(at1 + tid8, &Abuf[0][4096] + widA);
    glds16(at1 + 2048 + tid8, &Abuf[0][6144] + widA);
    const unsigned short* ws = wtile(0);
    glds16(ws + tid8, &Wbuf[0][0] + widA);
    glds16(ws + 2048 + tid8, &Wbuf[0][2048] + widA);
    glds4(ws + 4096 + tid2, &Wbuf[0][4096] + wid128);
    glds4(ws + 4608 + tid2, &Wbuf[0][4608] + wid128);
  }

// compute one kw step: 4 A/B b128 reads + ... per ks; 8 MFMA total
#define CHALF(AB_, WB_, KW_)                                                  \
  {                                                                           \
    _Pragma("unroll") for (int ks = 0; ks < 2; ++ks) {                        \
      const bf16x8 a0 = *(const bf16x8*)((AB_) + aoff[0][ks]);                \
      const bf16x8 a1 = *(const bf16x8*)((AB_) + aoff[1][ks]);                \
      bf16x8 bfr[2];                                                          \
      _Pragma("unroll") for (int nt = 0; nt < 2; ++nt) {                      \
        const int wcoln = nwl[nt] + (KW_) + 2;                                \
        bfr[nt] = *(const bf16x8*)((WB_) + (ndh[nt] * 80 + wcoln) * 64 +      \
                                   (((ks * 2 + hi2) ^ swz4(wcoln)) << 4));    \
      }                                                                       \
      acc[0][0] = __builtin_amdgcn_mfma_f32_32x32x16_bf16(a0, bfr[0],         \
                                                          acc[0][0], 0, 0, 0);\
      acc[0][1] = __builtin_amdgcn_mfma_f32_32x32x16_bf16(a0, bfr[1],         \
                                                          acc[0][1], 0, 0, 0);\
      acc[1][0] = __builtin_amdgcn_mfma_f32_32x32x16_bf16(a1, bfr[0],         \
                                                          acc[1][0], 0, 0, 0);\
      acc[1][1] = __builtin_amdgcn_mfma_f32_32x32x16_bf16(a1, bfr[1],         \
                                                          acc[1][1], 0, 0, 0);\
    }                                                                         \
  }

// one phase = 2 kw steps per barrier pair. WRT: 0 none, 1/2 g16 round, 3 g4x2
#define PHASE(PH, KWA, WBA, KWB, WBB, WRT, WSRCP, WDB)                        \
  {                                                                           \
    {                                                                         \
      int sn0 = S0 + 2 * (PH) + 2;                                            \
      if (sn0 >= 1352) sn0 -= 1352;                                           \
      int sn1 = sn0 + 1;                                                      \
      if (sn1 >= 1352) sn1 -= 1352;                                           \
      const unsigned short* at0 = Wp + ((c2base + (size_t)sn0) << 12);        \
      const unsigned short* at1 = Wp + ((c2base + (size_t)sn1) << 12);        \
      unsigned short* ad = &Abuf[((PH) + 1) & 1][0];                          \
      glds16(at0 + tid8, ad + widA);                                          \
      glds16(at0 + 2048 + tid8, ad + 2048 + widA);                            \
      glds16(at1 + tid8, ad + 4096 + widA);                                   \
      glds16(at1 + 2048 + tid8, ad + 6144 + widA);                            \
    }                                                                         \
    if ((WRT) == 1) glds16((WSRCP) + tid8, &Wbuf[(WDB)][0] + widA);           \
    if ((WRT) == 2)                                                           \
      glds16((WSRCP) + 2048 + tid8, &Wbuf[(WDB)][2048] + widA);               \
    if ((WRT) == 3) {                                                         \
      glds4((WSRCP) + 4096 + tid2, &Wbuf[(WDB)][4096] + wid128);              \
      glds4((WSRCP) + 4608 + tid2, &Wbuf[(WDB)][4608] + wid128);              \
    }                                                                         \
    vmwait<((WRT) == 0 ? 4 : ((WRT) == 3 ? 6 : 5))>();                        \
    __builtin_amdgcn_s_barrier();                                             \
    asm volatile("" ::: "memory");                                            \
    {                                                                         \
      const char* abA = (const char*)&Abuf[(PH) & 1][0];                      \
      const char* abB = abA + 8192;                                           \
      const char* wbA = (const char*)&Wbuf[(WBA)][0];                         \
      const char* wbB = (const char*)&Wbuf[(WBB)][0];                         \
      __builtin_amdgcn_s_setprio(1);                                          \
      CHALF(abA, wbA, KWA)                                                    \
      CHALF(abB, wbB, KWB)                                                    \
      __builtin_amdgcn_s_setprio(0);                                          \
    }                                                                         \
    asm volatile("s_waitcnt lgkmcnt(0)" ::: "memory");                        \
    __builtin_amdgcn_s_barrier();                                             \
  }

  // 26 u-iterations x 4 tiles (52 steps, 26 phases) — all parities static
  for (int u = 0; u < 26; ++u) {
    const int S0 = u * 52;
    const int Tb = u * 4;
    const unsigned short* wt1 = wtile(Tb + 1);
    const unsigned short* wt2 = wtile(Tb + 2);
    const unsigned short* wt3 = wtile(Tb + 3);
    const unsigned short* wt4 = wtile((Tb + 4 == 104) ? 0 : Tb + 4);
    PHASE(0, 0, 0, 1, 0, 0, wt1, 1)
    PHASE(1, 2, 0, 3, 0, 0, wt1, 1)
    PHASE(2, 4, 0, 5, 0, 0, wt1, 1)
    PHASE(3, 6, 0, 7, 0, 1, wt1, 1)
    PHASE(4, 8, 0, 9, 0, 2, wt1, 1)
    PHASE(5, 10, 0, 11, 0, 3, wt1, 1)
    PHASE(6, 12, 0, 0, 1, 0, wt1, 1)
    PHASE(7, 1, 1, 2, 1, 0, wt2, 0)
    PHASE(8, 3, 1, 4, 1, 0, wt2, 0)
    PHASE(9, 5, 1, 6, 1, 1, wt2, 0)
    PHASE(10, 7, 1, 8, 1, 2, wt2, 0)
    PHASE(11, 9, 1, 10, 1, 3, wt2, 0)
    PHASE(12, 11, 1, 12, 1, 0, wt2, 0)
    PHASE(13, 0, 0, 1, 0, 0, wt3, 1)
    PHASE(14, 2, 0, 3, 0, 0, wt3, 1)
    PHASE(15, 4, 0, 5, 0, 0, wt3, 1)
    PHASE(16, 6, 0, 7, 0, 1, wt3, 1)
    PHASE(17, 8, 0, 9, 0, 2, wt3, 1)
    PHASE(18, 10, 0, 11, 0, 3, wt3, 1)
    PHASE(19, 12, 0, 0, 1, 0, wt3, 1)
    PHASE(20, 1, 1, 2, 1, 0, wt4, 0)
    PHASE(21, 3, 1, 4, 1, 0, wt4, 0)
    PHASE(22, 5, 1, 6, 1, 1, wt4, 0)
    PHASE(23, 7, 1, 8, 1, 2, wt4, 0)
    PHASE(24, 9, 1, 10, 1, 3, wt4, 0)
    PHASE(25, 11, 1, 12, 1, 0, wt4, 0)
  }
#undef PHASE
#undef CHALF

  vmwait<0>();  // drain dangling prefetches

  // ---- epilogue: BN + SiLU.
  // 32x32 C/D layout (m74/m101): col = lane&31, row = (r&3)+8*(r>>2)+4*(lane>>5)
#pragma unroll
  for (int mt = 0; mt < 2; ++mt) {
#pragma unroll
    for (int nt = 0; nt < 2; ++nt) {
      const int n = wc * 64 + nt * 32 + l31;
      const int hh = h0 + (n >> 6), ww = n & 63;
#pragma unroll
      for (int r = 0; r < 16; ++r) {
        const int mloc = (r & 3) + 8 * (r >> 2) + 4 * hi2;
        const int c2l = wr * 64 + mt * 32 + mloc;
        const float y = acc[mt][nt][r] * s_scale[c2l] + s_shift[c2l];
        out[((size_t)(b * 256 + c2t * 128 + c2l)) * 4096 + hh * 64 + ww] =
            y / (1.f + __expf(-y));
      }
    }
  }
}

// ---------------------------------------------------------------------------
// Safety-net fallback if workspace is too small for packed buffers.
// ---------------------------------------------------------------------------
__global__ void naive_conv_kernel(
    const float* __restrict__ x, const float* __restrict__ W,
    const float* __restrict__ gamma, const float* __restrict__ beta,
    const float* __restrict__ mean, const float* __restrict__ var,
    float* __restrict__ out) {
  const int idx = blockIdx.x * 256 + threadIdx.x;
  if (idx >= 8 * 256 * 64 * 64) return;
  const int w = idx & 63, h = (idx >> 6) & 63;
  const int c2 = (idx >> 12) & 255, b = idx >> 20;
  float s = 0.f;
  for (int c1 = 0; c1 < 256; ++c1) {
    const float* xp = x + ((size_t)(b * 256 + c1) * 4096);
    const float* wp = W + ((size_t)(c2 * 256 + c1) * 169);
    for (int kh = 0; kh < 13; ++kh) {
      const int r = h + kh - 6;
      if ((unsigned)r >= 64u) continue;
      for (int kw = 0; kw < 13; ++kw) {
        const int c = w + kw - 6;
        if ((unsigned)c >= 64u) continue;
        s += xp[r * 64 + c] * wp[kh * 13 + kw];
      }
    }
  }
  const float inv = gamma[c2] * rsqrtf(var[c2] + EPS);
  const float y = s * inv + (beta[c2] - mean[c2] * inv);
  out[idx] = y / (1.f + __expf(-y));
}

extern "C" void kernel_launch(void* const* d_in, const int* in_sizes, int n_in,
                              void* d_out, int out_size, void* d_ws, size_t ws_size,
                              hipStream_t stream) {
  const float* x = (const float*)d_in[0];
  const float* W = (const float*)d_in[1];
  const float* gamma = (const float*)d_in[2];
  const float* beta = (const float*)d_in[3];
  const float* mean = (const float*)d_in[4];
  const float* var = (const float*)d_in[5];
  float* out = (float*)d_out;

  const size_t WP_BYTES = (size_t)256 * 43264 * 2;  // 22,151,168
  const size_t XT_BYTES = (size_t)12455424 * 2;     // 24,910,848

  if (ws_size >= WP_BYTES + XT_BYTES) {
    unsigned short* Wp = (unsigned short*)d_ws;
    unsigned short* xT = (unsigned short*)((char*)d_ws + WP_BYTES);
    pack_w_kernel<<<256 * 13, 256, 0, stream>>>(W, Wp);
    pack_xt_kernel<<<8 * 8 * 76, 256, 0, stream>>>(x, xT);
    conv5_kernel<<<512, 256, 0, stream>>>(Wp, xT, gamma, beta, mean, var, out);
  } else {
    naive_conv_kernel<<<(8 * 256 * 64 * 64 + 255) / 256, 256, 0, stream>>>(
        x, W, gamma, beta, mean, var, out);
  }
}

// Round 6
// 623.993 us; speedup vs baseline: 1.6016x; 1.0283x over previous
//
#include <hip/hip_runtime.h>
#include <stdint.h>

#define EPS 1e-5f

typedef __attribute__((ext_vector_type(8))) __bf16 bf16x8;
typedef __attribute__((ext_vector_type(16))) float f32x16;

__device__ __forceinline__ int swz4(int r) { return (r ^ (r >> 2)) & 3; }

__device__ __forceinline__ unsigned short f2bf(float f) {
  union { float f; unsigned u; } v; v.f = f;
  unsigned r = v.u + 0x7fffu + ((v.u >> 16) & 1u);
  return (unsigned short)(r >> 16);
}

__device__ __forceinline__ void glds16(const unsigned short* g, unsigned short* l) {
  __builtin_amdgcn_global_load_lds(
      (const __attribute__((address_space(1))) void*)g,
      (__attribute__((address_space(3))) void*)l, 16, 0, 0);
}
__device__ __forceinline__ void glds4(const unsigned short* g, unsigned short* l) {
  __builtin_amdgcn_global_load_lds(
      (const __attribute__((address_space(1))) void*)g,
      (__attribute__((address_space(3))) void*)l, 4, 0, 0);
}

template <int N>
__device__ __forceinline__ void vmwait() {
  asm volatile("s_waitcnt vmcnt(%0)" ::"n"(N) : "memory");
}

// ---------------------------------------------------------------------------
// Pack W [c2][c1][13][13] f32 -> bf16 per-K-step tiles = exact linear LDS
// image of the A tile (chunk swizzle baked in).
// K order: k = ((kh*8 + c1c)*13 + kw)*32 + c1i
// ---------------------------------------------------------------------------
__global__ __launch_bounds__(256) void pack_w_kernel(
    const float* __restrict__ W, unsigned short* __restrict__ Wp) {
  const int blk = blockIdx.x;  // c2*13 + kh
  const int c2 = blk / 13, kh = blk - c2 * 13;
  const int c1 = threadIdx.x;
  const int c2t = c2 >> 7, m = c2 & 127;
  const int c1c = c1 >> 5, c1i = c1 & 31;
  const float* src = W + (((size_t)(c2 * 256 + c1)) * 13 + kh) * 13;
  const int rowoff = (((c1i >> 3) ^ swz4(m)) << 3) + (c1i & 7);
#pragma unroll
  for (int kw = 0; kw < 13; ++kw) {
    const int ks = (kh * 8 + c1c) * 13 + kw;
    const size_t dst = (((size_t)c2t * 1352 + ks) * 128 + m) * 32 + rowoff;
    Wp[dst] = f2bf(src[kw]);
  }
}

// ---------------------------------------------------------------------------
// Pack x [b][c1][64][64] f32 -> xT[b][c1c][rowp 76][colp 80][c1i 32] bf16,
// zero-padded halo (rowp = row+6, colp = ic+8), chunk swizzle baked in.
// ---------------------------------------------------------------------------
__global__ __launch_bounds__(256) void pack_xt_kernel(
    const float* __restrict__ x, unsigned short* __restrict__ xT) {
  const int blk = blockIdx.x;  // (b*8 + c1c)*76 + rowp ; 4864 blocks
  const int rowp = blk % 76;
  const int bc = blk / 76;
  const int c1c = bc & 7, b = bc >> 3;
  const int row = rowp - 6;
  const bool rok = (unsigned)row < 64u;
  unsigned short* dst = xT + (size_t)blk * 2560;
  const float* srcb = x + (size_t)(b * 256 + c1c * 32) * 4096 +
                      (rok ? row * 64 : 0);
#pragma unroll
  for (int e = 0; e < 10; ++e) {
    const int idx = e * 256 + threadIdx.x;  // 0..2559
    const int colp = idx >> 5, c1i = idx & 31;
    const int ic = colp - 8;
    const float v = (rok && (unsigned)ic < 64u) ? srcb[(size_t)c1i * 4096 + ic] : 0.f;
    dst[colp * 32 + ((((c1i >> 3) ^ swz4(colp)) << 3)) + (c1i & 7)] = f2bf(v);
  }
}

// ---------------------------------------------------------------------------
// Implicit-GEMM conv + BN + SiLU.
// Block: 256 thr (4 waves 2M x 2N), tile 128 c2 x 128 sp (2h x 64w).
// Wave tile 64x64 via 32x32x16 MFMA. Grid 512 -> 2 independent blocks/CU.
// m201-style phases: S1 {ds_read frags -> regs, issue glds} | bar |
// pure-register MFMA | counted vmwait | bar.
// ---------------------------------------------------------------------------
__global__ __launch_bounds__(256, 2) void conv6_kernel(
    const unsigned short* __restrict__ Wp, const unsigned short* __restrict__ xT,
    const float* __restrict__ gamma, const float* __restrict__ beta,
    const float* __restrict__ mean, const float* __restrict__ var,
    float* __restrict__ out) {
  __shared__ __align__(16) unsigned short Abuf[2][8192];  // 2 x 16 KiB (2 tiles each)
  __shared__ __align__(16) unsigned short Wbuf[2][5120];  // 2 x 10 KiB (2 rows)
  __shared__ float s_scale[128], s_shift[128];

  const int tid = threadIdx.x;
  const int bid = blockIdx.x;
  const int b = bid & 7;  // XCD-aware: blocks on XCD k share batch image k
  const int h0 = ((bid >> 3) & 31) * 2;
  const int c2t = bid >> 8;

  const int wid = tid >> 6, lane = tid & 63;
  const int wr = wid >> 1, wc = wid & 1;
  const int l31 = lane & 31, hi2 = lane >> 5;

  if (tid < 128) {
    const int c2 = c2t * 128 + tid;
    const float inv = gamma[c2] * rsqrtf(var[c2] + EPS);
    s_scale[tid] = inv;
    s_shift[tid] = beta[c2] - mean[c2] * inv;
  }

  // A-fragment byte offsets within a 4096-ushort tile
  int aoff[2][2];
#pragma unroll
  for (int mt = 0; mt < 2; ++mt)
#pragma unroll
    for (int ks = 0; ks < 2; ++ks) {
      const int m = wr * 64 + mt * 32 + l31;
      aoff[mt][ks] = m * 64 + (((ks * 2 + hi2) ^ swz4(m)) << 4);
    }
  int ndh[2], nwl[2];
#pragma unroll
  for (int nt = 0; nt < 2; ++nt) {
    const int n = wc * 64 + nt * 32 + l31;
    ndh[nt] = n >> 6;
    nwl[nt] = n & 63;
  }

  const int tid8 = tid * 8, tid2 = tid * 2;
  const int widA = wid * 512, wid128 = wid * 128;

  const size_t c2base = (size_t)c2t * 1352;
  const int bc8 = b * 8;

  auto wtile = [&](int T) -> const unsigned short* {
    const int kh = T >> 3, c1c = T & 7;
    return xT + (size_t)((bc8 + c1c) * 76 + h0 + kh) * 2560;
  };

  f32x16 acc[2][2];
#pragma unroll
  for (int i = 0; i < 2; ++i)
#pragma unroll
    for (int j = 0; j < 2; ++j)
#pragma unroll
      for (int r = 0; r < 16; ++r) acc[i][j][r] = 0.f;

  // fragment registers for one phase (2 kw-steps): [step][ks][mt/nt]
  bf16x8 rA[2][2][2], rB[2][2][2];

  // ---- prologue: A steps 0,1 -> Abuf[0]; window tile0 -> Wbuf[0]
  {
    const unsigned short* at0 = Wp + (c2base << 12);
    const unsigned short* at1 = Wp + ((c2base + 1) << 12);
    glds16(at0 + tid8, &Abuf[0][0] + widA);
    glds16(at0 + 2048 + tid8, &Abuf[0][2048] + widA);
    glds16(at1 + tid8, &Abuf[0][4096] + widA);
    glds16(at1 + 2048 + tid8, &Abuf[0][6144] + widA);
    const unsigned short* ws = wtile(0);
    glds16(ws + tid8, &Wbuf[0][0] + widA);
    glds16(ws + 2048 + tid8, &Wbuf[0][2048] + widA);
    glds4(ws + 4096 + tid2, &Wbuf[0][4096] + wid128);
    glds4(ws + 4608 + tid2, &Wbuf[0][4608] + wid128);
    vmwait<0>();
    __builtin_amdgcn_s_barrier();
  }

// one phase = 2 kw steps. S1: 16 ds_read -> regs + prefetch glds; bar;
// pure-reg MFMA x16; vmwait<w_p>; bar.  WRT: 0 none, 1/2 g16 round, 3 g4x2
#define PHASE(PH, KWA, WBA, KWB, WBB, WRT, WSRCP, WDB)                        \
  {                                                                           \
    /* ---- S1: fragment reads for THIS phase (buffers filled last phase) */  \
    {                                                                         \
      const char* abA = (const char*)&Abuf[(PH) & 1][0];                      \
      const char* abB = abA + 8192;                                           \
      const char* wbA = (const char*)&Wbuf[(WBA)][0];                         \
      const char* wbB = (const char*)&Wbuf[(WBB)][0];                         \
      _Pragma("unroll") for (int ks = 0; ks < 2; ++ks) {                      \
        rA[0][ks][0] = *(const bf16x8*)(abA + aoff[0][ks]);                   \
        rA[0][ks][1] = *(const bf16x8*)(abA + aoff[1][ks]);                   \
        rA[1][ks][0] = *(const bf16x8*)(abB + aoff[0][ks]);                   \
        rA[1][ks][1] = *(const bf16x8*)(abB + aoff[1][ks]);                   \
        _Pragma("unroll") for (int nt = 0; nt < 2; ++nt) {                    \
          const int colA = nwl[nt] + (KWA) + 2;                               \
          rB[0][ks][nt] = *(const bf16x8*)(                                   \
              wbA + (ndh[nt] * 80 + colA) * 64 +                              \
              (((ks * 2 + hi2) ^ swz4(colA)) << 4));                          \
          const int colB = nwl[nt] + (KWB) + 2;                               \
          rB[1][ks][nt] = *(const bf16x8*)(                                   \
              wbB + (ndh[nt] * 80 + colB) * 64 +                              \
              (((ks * 2 + hi2) ^ swz4(colB)) << 4));                          \
        }                                                                     \
      }                                                                       \
    }                                                                         \
    /* ---- prefetch: A for next phase; window round per WRT */               \
    {                                                                         \
      int sn0 = S0 + 2 * (PH) + 2;                                            \
      if (sn0 >= 1352) sn0 -= 1352;                                           \
      int sn1 = sn0 + 1;                                                      \
      if (sn1 >= 1352) sn1 -= 1352;                                           \
      const unsigned short* at0 = Wp + ((c2base + (size_t)sn0) << 12);        \
      const unsigned short* at1 = Wp + ((c2base + (size_t)sn1) << 12);        \
      unsigned short* ad = &Abuf[((PH) + 1) & 1][0];                          \
      glds16(at0 + tid8, ad + widA);                                          \
      glds16(at0 + 2048 + tid8, ad + 2048 + widA);                            \
      glds16(at1 + tid8, ad + 4096 + widA);                                   \
      glds16(at1 + 2048 + tid8, ad + 6144 + widA);                            \
    }                                                                         \
    if ((WRT) == 1) glds16((WSRCP) + tid8, &Wbuf[(WDB)][0] + widA);           \
    if ((WRT) == 2)                                                           \
      glds16((WSRCP) + 2048 + tid8, &Wbuf[(WDB)][2048] + widA);               \
    if ((WRT) == 3) {                                                         \
      glds4((WSRCP) + 4096 + tid2, &Wbuf[(WDB)][4096] + wid128);              \
      glds4((WSRCP) + 4608 + tid2, &Wbuf[(WDB)][4608] + wid128);              \
    }                                                                         \
    asm volatile("" ::: "memory"); /* keep S1 reads above the barrier */      \
    __builtin_amdgcn_s_barrier();                                             \
    __builtin_amdgcn_sched_barrier(0); /* pin: nothing crosses */             \
    /* ---- pure-register MFMA cluster (compiler inserts lgkm waits) */       \
    {                                                                         \
      __builtin_amdgcn_s_setprio(1);                                          \
      _Pragma("unroll") for (int s = 0; s < 2; ++s)                           \
          _Pragma("unroll") for (int ks = 0; ks < 2; ++ks) {                  \
        acc[0][0] = __builtin_amdgcn_mfma_f32_32x32x16_bf16(                  \
            rA[s][ks][0], rB[s][ks][0], acc[0][0], 0, 0, 0);                  \
        acc[0][1] = __builtin_amdgcn_mfma_f32_32x32x16_bf16(                  \
            rA[s][ks][0], rB[s][ks][1], acc[0][1], 0, 0, 0);                  \
        acc[1][0] = __builtin_amdgcn_mfma_f32_32x32x16_bf16(                  \
            rA[s][ks][1], rB[s][ks][0], acc[1][0], 0, 0, 0);                  \
        acc[1][1] = __builtin_amdgcn_mfma_f32_32x32x16_bf16(                  \
            rA[s][ks][1], rB[s][ks][1], acc[1][1], 0, 0, 0);                  \
      }                                                                       \
      __builtin_amdgcn_s_setprio(0);                                          \
    }                                                                         \
    /* drain: leave only this phase's window ops (newest) in flight */        \
    vmwait<((WRT) == 0 ? 0 : ((WRT) == 3 ? 2 : 1))>();                        \
    __builtin_amdgcn_s_barrier();                                             \
  }

  // 26 u-iterations x 4 tiles (52 steps, 26 phases) — all parities static
  for (int u = 0; u < 26; ++u) {
    const int S0 = u * 52;
    const int Tb = u * 4;
    const unsigned short* wt1 = wtile(Tb + 1);
    const unsigned short* wt2 = wtile(Tb + 2);
    const unsigned short* wt3 = wtile(Tb + 3);
    const unsigned short* wt4 = wtile((Tb + 4 == 104) ? 0 : Tb + 4);
    PHASE(0, 0, 0, 1, 0, 0, wt1, 1)
    PHASE(1, 2, 0, 3, 0, 0, wt1, 1)
    PHASE(2, 4, 0, 5, 0, 0, wt1, 1)
    PHASE(3, 6, 0, 7, 0, 1, wt1, 1)
    PHASE(4, 8, 0, 9, 0, 2, wt1, 1)
    PHASE(5, 10, 0, 11, 0, 3, wt1, 1)
    PHASE(6, 12, 0, 0, 1, 0, wt1, 1)
    PHASE(7, 1, 1, 2, 1, 0, wt2, 0)
    PHASE(8, 3, 1, 4, 1, 0, wt2, 0)
    PHASE(9, 5, 1, 6, 1, 1, wt2, 0)
    PHASE(10, 7, 1, 8, 1, 2, wt2, 0)
    PHASE(11, 9, 1, 10, 1, 3, wt2, 0)
    PHASE(12, 11, 1, 12, 1, 0, wt2, 0)
    PHASE(13, 0, 0, 1, 0, 0, wt3, 1)
    PHASE(14, 2, 0, 3, 0, 0, wt3, 1)
    PHASE(15, 4, 0, 5, 0, 0, wt3, 1)
    PHASE(16, 6, 0, 7, 0, 1, wt3, 1)
    PHASE(17, 8, 0, 9, 0, 2, wt3, 1)
    PHASE(18, 10, 0, 11, 0, 3, wt3, 1)
    PHASE(19, 12, 0, 0, 1, 0, wt3, 1)
    PHASE(20, 1, 1, 2, 1, 0, wt4, 0)
    PHASE(21, 3, 1, 4, 1, 0, wt4, 0)
    PHASE(22, 5, 1, 6, 1, 1, wt4, 0)
    PHASE(23, 7, 1, 8, 1, 2, wt4, 0)
    PHASE(24, 9, 1, 10, 1, 3, wt4, 0)
    PHASE(25, 11, 1, 12, 1, 0, wt4, 0)
  }
#undef PHASE

  vmwait<0>();  // drain dangling prefetches

  // ---- epilogue: BN + SiLU.
  // 32x32 C/D layout (m74/m101): col = lane&31, row = (r&3)+8*(r>>2)+4*(lane>>5)
#pragma unroll
  for (int mt = 0; mt < 2; ++mt) {
#pragma unroll
    for (int nt = 0; nt < 2; ++nt) {
      const int n = wc * 64 + nt * 32 + l31;
      const int hh = h0 + (n >> 6), ww = n & 63;
#pragma unroll
      for (int r = 0; r < 16; ++r) {
        const int mloc = (r & 3) + 8 * (r >> 2) + 4 * hi2;
        const int c2l = wr * 64 + mt * 32 + mloc;
        const float y = acc[mt][nt][r] * s_scale[c2l] + s_shift[c2l];
        out[((size_t)(b * 256 + c2t * 128 + c2l)) * 4096 + hh * 64 + ww] =
            y / (1.f + __expf(-y));
      }
    }
  }
}

// ---------------------------------------------------------------------------
// Safety-net fallback if workspace is too small for packed buffers.
// ---------------------------------------------------------------------------
__global__ void naive_conv_kernel(
    const float* __restrict__ x, const float* __restrict__ W,
    const float* __restrict__ gamma, const float* __restrict__ beta,
    const float* __restrict__ mean, const float* __restrict__ var,
    float* __restrict__ out) {
  const int idx = blockIdx.x * 256 + threadIdx.x;
  if (idx >= 8 * 256 * 64 * 64) return;
  const int w = idx & 63, h = (idx >> 6) & 63;
  const int c2 = (idx >> 12) & 255, b = idx >> 20;
  float s = 0.f;
  for (int c1 = 0; c1 < 256; ++c1) {
    const float* xp = x + ((size_t)(b * 256 + c1) * 4096);
    const float* wp = W + ((size_t)(c2 * 256 + c1) * 169);
    for (int kh = 0; kh < 13; ++kh) {
      const int r = h + kh - 6;
      if ((unsigned)r >= 64u) continue;
      for (int kw = 0; kw < 13; ++kw) {
        const int c = w + kw - 6;
        if ((unsigned)c >= 64u) continue;
        s += xp[r * 64 + c] * wp[kh * 13 + kw];
      }
    }
  }
  const float inv = gamma[c2] * rsqrtf(var[c2] + EPS);
  const float y = s * inv + (beta[c2] - mean[c2] * inv);
  out[idx] = y / (1.f + __expf(-y));
}

extern "C" void kernel_launch(void* const* d_in, const int* in_sizes, int n_in,
                              void* d_out, int out_size, void* d_ws, size_t ws_size,
                              hipStream_t stream) {
  const float* x = (const float*)d_in[0];
  const float* W = (const float*)d_in[1];
  const float* gamma = (const float*)d_in[2];
  const float* beta = (const float*)d_in[3];
  const float* mean = (const float*)d_in[4];
  const float* var = (const float*)d_in[5];
  float* out = (float*)d_out;

  const size_t WP_BYTES = (size_t)256 * 43264 * 2;  // 22,151,168
  const size_t XT_BYTES = (size_t)12455424 * 2;     // 24,910,848

  if (ws_size >= WP_BYTES + XT_BYTES) {
    unsigned short* Wp = (unsigned short*)d_ws;
    unsigned short* xT = (unsigned short*)((char*)d_ws + WP_BYTES);
    pack_w_kernel<<<256 * 13, 256, 0, stream>>>(W, Wp);
    pack_xt_kernel<<<8 * 8 * 76, 256, 0, stream>>>(x, xT);
    conv6_kernel<<<512, 256, 0, stream>>>(Wp, xT, gamma, beta, mean, var, out);
  } else {
    naive_conv_kernel<<<(8 * 256 * 64 * 64 + 255) / 256, 256, 0, stream>>>(
        x, W, gamma, beta, mean, var, out);
  }
}